// Round 5
// baseline (241.183 us; speedup 1.0000x reference)
//
#include <hip/hip_runtime.h>
#include <stdint.h>
#include <math.h>

static constexpr int NIMG  = 16;
static constexpr int HH    = 512;
static constexpr int WW    = 512;
static constexpr int TOTAL = NIMG * HH * WW;       // 4,194,304
static constexpr int WPR   = WW / 64;              // 8 qwords per row
static constexpr int QPI   = HH * WPR;             // 4096 qwords per image
static constexpr int NQ    = TOTAL / 64;           // 65,536

static constexpr int S       = 16;                 // strips per image
static constexpr int RPS     = HH / S;             // 32 owned rows per strip
static constexpr int HALO    = 8;                  // halo rows each side
static constexpr int LROWS   = RPS + 2 * HALO;     // 48 rows in LDS
static constexpr int LQ      = LROWS * WPR;        // 384 qwords
static constexpr int REGION  = (LROWS - 2) * WPR;  // 368 computable qwords
static constexpr int NTHR    = 384;                // threads per skel block
static constexpr int NBLK    = NIMG * S;           // 256 blocks
static constexpr int MAXCHUNK = 32;                // 32 chunks x 4 iters = 128 iters
static constexpr int CSUB    = HALO;               // 8 substeps per chunk

// control ints
static constexpr int CI_FLAG   = 0;                           // NIMG*MAXCHUNK
static constexpr int CI_DONE   = CI_FLAG + NIMG * MAXCHUNK;
static constexpr int CI_CONV   = CI_DONE + NIMG * MAXCHUNK;   // NIMG
static constexpr int CI_PSEQ   = CI_CONV + NIMG;              // NBLK
static constexpr int CI_TICKET = CI_PSEQ + NBLK;              // 1
static constexpr int CTRL_INTS = CI_TICKET + 1;

// workspace layout (bytes)
static constexpr size_t OFF_PACK = 0;                                     // u64[NQ]
static constexpr size_t OFF_CTRL = (size_t)NQ * 8;
static constexpr size_t OFF_PART = (OFF_CTRL + (size_t)CTRL_INTS * 4 + 7) & ~(size_t)7;
static constexpr size_t OFF_HT   = OFF_PART + (size_t)NBLK * 2 * 8;       // u64[NBLK*2*64]
static constexpr size_t OFF_HB   = OFF_HT + (size_t)NBLK * 2 * HALO * WPR * 8;

#define LD_ACQ(p)   __hip_atomic_load((p), __ATOMIC_ACQUIRE, __HIP_MEMORY_SCOPE_AGENT)
#define LD_RLX(p)   __hip_atomic_load((p), __ATOMIC_RELAXED, __HIP_MEMORY_SCOPE_AGENT)
#define ST_REL(p,v) __hip_atomic_store((p), (v), __ATOMIC_RELEASE, __HIP_MEMORY_SCOPE_AGENT)
#define ST_RLX(p,v) __hip_atomic_store((p), (v), __ATOMIC_RELAXED, __HIP_MEMORY_SCOPE_AGENT)

// gaussian taps exactly like numpy (f64 exp, sequential /sum, cast f32) — proven bit-compatible
__device__ __forceinline__ void make_gk(float* gks) {
    if (threadIdx.x < 9) {
        double ssum = 0.0;
        for (int i = 0; i < 9; ++i) { double x = (double)(i - 4); ssum += exp(-0.5 * x * x); }
        double x = (double)((int)threadIdx.x - 4);
        gks[threadIdx.x] = (float)(exp(-0.5 * x * x) / ssum);
    }
}

// --- fused separable blur + threshold + bit-pack. 64x64 output tile per block.
__global__ void __launch_bounds__(256) fused_blur(const float* __restrict__ gt,
                                                  uint64_t* __restrict__ packed,
                                                  int* __restrict__ ctrl) {
    __shared__ float tin[72 * 72];
    __shared__ float tv[64 * 72];
    __shared__ float gks[9];
    const int tid = threadIdx.x;
    if (blockIdx.x == 0) {
        for (int i = tid; i < CTRL_INTS; i += 256) ctrl[i] = 0;
    }
    make_gk(gks);
    const int img  = blockIdx.x >> 6;
    const int tile = blockIdx.x & 63;
    const int oy = (tile >> 3) << 6, ox = (tile & 7) << 6;
    const float* G = gt + (size_t)img * (HH * WW);
    for (int i = tid; i < 72 * 72; i += 256) {
        int r = i / 72, c = i - r * 72;
        int gy = oy - 4 + r, gx = ox - 4 + c;
        gy = gy < 0 ? -gy - 1 : (gy >= HH ? 2 * HH - 1 - gy : gy);   // symmetric pad
        gx = gx < 0 ? -gx - 1 : (gx >= WW ? 2 * WW - 1 - gx : gx);
        tin[i] = G[gy * WW + gx];
    }
    __syncthreads();
    for (int i = tid; i < 64 * 72; i += 256) {     // vertical pass (axis=1 first, like ref)
        int r = i / 72, c = i - r * 72;
        float s = 0.f;
#pragma unroll
        for (int t = 0; t < 9; ++t) s += gks[t] * tin[(r + t) * 72 + c];
        tv[i] = s;
    }
    __syncthreads();
    const int lane = tid & 63, w = tid >> 6;
    for (int j = 0; j < 16; ++j) {                 // horizontal pass + threshold + pack
        int yr = w * 16 + j;
        float s = 0.f;
#pragma unroll
        for (int t = 0; t < 9; ++t) s += gks[t] * tv[yr * 72 + lane + t];
        uint64_t m = __ballot(s > 0.1f);
        if (lane == 0) packed[(size_t)img * QPI + (oy + yr) * WPR + (ox >> 6)] = m;
    }
}

// full adder on 64 bit-lanes
__device__ __forceinline__ void fa(uint64_t a, uint64_t b, uint64_t c, uint64_t& s, uint64_t& cy) {
    uint64_t axb = a ^ b;
    s  = axb ^ c;
    cy = (a & b) | (c & axb);
}

// bit-sliced Zhang-Suen delete mask
__device__ __forceinline__ uint64_t zs_del(uint64_t cc, uint64_t nc, uint64_t sc, uint64_t cw, uint64_t ce,
                                           uint64_t nw, uint64_t ne, uint64_t sw, uint64_t se, int step) {
    uint64_t p2 = nc;
    uint64_t p3 = (nc >> 1) | (ne << 63);
    uint64_t p4 = (cc >> 1) | (ce << 63);
    uint64_t p5 = (sc >> 1) | (se << 63);
    uint64_t p6 = sc;
    uint64_t p7 = (sc << 1) | (sw >> 63);
    uint64_t p8 = (cc << 1) | (cw >> 63);
    uint64_t p9 = (nc << 1) | (nw >> 63);

    uint64_t s1, k1, s2, k2;
    fa(p2, p3, p4, s1, k1);
    fa(p5, p6, p7, s2, k2);
    uint64_t s3 = p8 ^ p9, k3 = p8 & p9;
    uint64_t b0, k4;
    fa(s1, s2, s3, b0, k4);
    uint64_t t1, t2;
    fa(k1, k2, k3, t1, t2);
    uint64_t b1 = t1 ^ k4;
    uint64_t k5 = t1 & k4;
    uint64_t b2 = t2 ^ k5;
    uint64_t b3 = t2 & k5;
    uint64_t condB = (b1 | b2 | b3) & ~(b3 | (b0 & b1 & b2));

    uint64_t q0 = ~p2 & p3, q1 = ~p3 & p4, q2 = ~p4 & p5, q3 = ~p5 & p6;
    uint64_t q4 = ~p6 & p7, q5 = ~p7 & p8, q6 = ~p8 & p9, q7 = ~p9 & p2;
    uint64_t u1, v1, u2, v2;
    fa(q0, q1, q2, u1, v1);
    fa(q3, q4, q5, u2, v2);
    uint64_t u3 = q6 ^ q7, v3 = q6 & q7;
    uint64_t a0, v4;
    fa(u1, u2, u3, a0, v4);
    uint64_t w1, w2;
    fa(v1, v2, v3, w1, w2);
    uint64_t a1 = w1 ^ v4;
    uint64_t ka = w1 & v4;
    uint64_t a2 = w2 ^ ka;
    uint64_t a3 = w2 & ka;
    uint64_t condA = a0 & ~a1 & ~a2 & ~a3;

    uint64_t nc1, nc2;
    if (step == 0) { nc1 = ~(p2 & p4 & p6); nc2 = ~(p4 & p6 & p8); }
    else           { nc1 = ~(p2 & p4 & p8); nc2 = ~(p2 & p6 & p8); }

    return cc & condB & condA & nc1 & nc2;
}

// --- halo-redundant strip thinning + fused loss reduction. Block = (img, strip).
__global__ void __launch_bounds__(NTHR) skel(const uint64_t* __restrict__ packed,
                                             const float4* __restrict__ pred4,
                                             const float4* __restrict__ gt4,
                                             int* __restrict__ ctrl, double* __restrict__ part,
                                             uint64_t* __restrict__ haloT, uint64_t* __restrict__ haloB,
                                             float* __restrict__ out) {
    __shared__ uint64_t SA[LQ];
    __shared__ uint64_t SB[LQ];
    __shared__ double sh0[512];
    __shared__ double sh1[512];
    __shared__ int chunkch, exitf, lastf;

    const int tid = threadIdx.x;
    const int img = blockIdx.x >> 4;
    const int s   = blockIdx.x & 15;
    const int myT = blockIdx.x;
    int* flag = ctrl + CI_FLAG;
    int* done = ctrl + CI_DONE;
    int* conv = ctrl + CI_CONV;
    int* pseq = ctrl + CI_PSEQ;
    int* tick = ctrl + CI_TICKET;
    const uint64_t* gimg = packed + (size_t)img * QPI;

    // load strip + halos (rows beyond image stay 0 and are self-sustaining: out ⊆ cc)
    {
        int lr = tid >> 3, wx = tid & 7;
        int gr = s * RPS - HALO + lr;
        SA[tid] = (gr >= 0 && gr < HH) ? gimg[gr * WPR + wx] : 0;
    }
    if (tid == 0) { chunkch = 0; exitf = 0; }
    __syncthreads();

    uint64_t* cur = SA;
    uint64_t* nxt = SB;
    int chacc = 0;

    for (int c = 0; c < MAXCHUNK; ++c) {
        // -- 8 substeps (4 full ZS iterations), validity frontier V_k = [k, 47-k] ⊇ owned [8,39]
        for (int k = 0; k < CSUB; ++k) {
            if (tid < REGION) {
                int lr = (tid >> 3) + 1, wx = tid & 7;
                int base = lr * WPR + wx;
                uint64_t cc = cur[base];
                uint64_t o = 0;
                if (cc) {
                    bool xw = wx > 0, xe = wx < WPR - 1;
                    uint64_t cw = xw ? cur[base - 1] : 0;
                    uint64_t ce = xe ? cur[base + 1] : 0;
                    uint64_t nc = cur[base - WPR];
                    uint64_t sc = cur[base + WPR];
                    uint64_t nw = xw ? cur[base - WPR - 1] : 0;
                    uint64_t ne = xe ? cur[base - WPR + 1] : 0;
                    uint64_t sw = xw ? cur[base + WPR - 1] : 0;
                    uint64_t se = xe ? cur[base + WPR + 1] : 0;
                    uint64_t del = zs_del(cc, nc, sc, cw, ce, nw, ne, sw, se, k & 1);
                    o = cc & ~del;
                    if (del && lr >= HALO && lr < HALO + RPS) chacc = 1;   // owned rows only
                }
                nxt[base] = o;
            }
            __syncthreads();
            uint64_t* t = cur; cur = nxt; nxt = t;
        }
        // -- chunk boundary: cur == SA
        if (__any(chacc) && (tid & 63) == 0) atomicOr(&chunkch, 1);
        const int p = (c + 1) & 1;
        if (tid < 64) {                       // publish top owned rows 8..15
            if (s > 0) ST_RLX(&haloT[(size_t)((myT << 1) | p) * 64 + tid], cur[(HALO + (tid >> 3)) * WPR + (tid & 7)]);
        } else if (tid < 128) {               // publish bottom owned rows 32..39
            int t2 = tid - 64;
            if (s < S - 1) ST_RLX(&haloB[(size_t)((myT << 1) | p) * 64 + t2], cur[(RPS + (t2 >> 3)) * WPR + (t2 & 7)]);
        }
        __threadfence();
        __syncthreads();
        if (tid == 0) {
            ST_REL(&pseq[myT], c + 1);        // unblock neighbors first
            int ch = chunkch;
            int fidx = img * MAXCHUNK + c;
            if (ch) __hip_atomic_fetch_or(&flag[fidx], 1, __ATOMIC_RELAXED, __HIP_MEMORY_SCOPE_AGENT);
            int pos = __hip_atomic_fetch_add(&done[fidx], 1, __ATOMIC_ACQ_REL, __HIP_MEMORY_SCOPE_AGENT);
            if (pos == S - 1) {
                int fv = ch ? 1 : LD_RLX(&flag[fidx]);
                if (!fv) ST_REL(&conv[img], 1);
            }
            if (LD_RLX(&conv[img])) exitf = 1;
            else if (s > 0) {
                while (LD_ACQ(&pseq[myT - 1]) <= c) {
                    if (LD_RLX(&conv[img])) { exitf = 1; break; }
                }
            }
        }
        if (tid == 64 && s < S - 1) {
            while (LD_ACQ(&pseq[myT + 1]) <= c) {
                if (LD_RLX(&conv[img])) { exitf = 1; break; }
            }
        }
        __syncthreads();
        if (exitf) break;                     // state at boundary c == converged state
        // -- load fresh halos (state after chunk c) and reset chunk flags
        if (tid < 64) {
            if (s > 0) SA[tid] = LD_RLX(&haloB[(size_t)(((myT - 1) << 1) | p) * 64 + tid]);
        } else if (tid < 128) {
            int t2 = tid - 64;
            if (s < S - 1) SA[(RPS + HALO) * WPR + t2] = LD_RLX(&haloT[(size_t)(((myT + 1) << 1) | p) * 64 + t2]);
        }
        if (tid == 0) chunkch = 0;
        chacc = 0;
        __syncthreads();
    }

    // -- fused loss reduction over this strip (mask = owned rows 8..39 of cur, in LDS)
    double a0 = 0.0, a1 = 0.0;
    const float4* P = pred4 + (size_t)img * (HH * WW / 4) + (size_t)s * RPS * (WW / 4);
    const float4* G = gt4   + (size_t)img * (HH * WW / 4) + (size_t)s * RPS * (WW / 4);
    for (int i = tid; i < RPS * WW / 4; i += NTHR) {
        float4 pv = P[i];
        float4 gv = G[i];
        uint64_t mq = cur[(HALO + (i >> 7)) * WPR + ((i & 127) >> 4)];
        int shb = (i & 15) << 2;
        double d, d2;
        d = (double)(pv.x - gv.x); d2 = d * d; a0 += d2; if ((mq >> (shb    )) & 1) a1 += d2;
        d = (double)(pv.y - gv.y); d2 = d * d; a0 += d2; if ((mq >> (shb + 1)) & 1) a1 += d2;
        d = (double)(pv.z - gv.z); d2 = d * d; a0 += d2; if ((mq >> (shb + 2)) & 1) a1 += d2;
        d = (double)(pv.w - gv.w); d2 = d * d; a0 += d2; if ((mq >> (shb + 3)) & 1) a1 += d2;
    }
    sh0[tid] = a0;
    sh1[tid] = a1;
    if (tid < 128) { sh0[NTHR + tid] = 0.0; sh1[NTHR + tid] = 0.0; }
    __syncthreads();
    for (int off = 256; off > 0; off >>= 1) {
        if (tid < off) { sh0[tid] += sh0[tid + off]; sh1[tid] += sh1[tid + off]; }
        __syncthreads();
    }
    if (tid == 0) {
        ST_RLX(&part[2 * myT],     sh0[0]);
        ST_RLX(&part[2 * myT + 1], sh1[0]);
        int pos = __hip_atomic_fetch_add(tick, 1, __ATOMIC_ACQ_REL, __HIP_MEMORY_SCOPE_AGENT);
        lastf = (pos == NBLK - 1);
    }
    __syncthreads();
    if (lastf) {
        double a = 0.0;
        if (tid < NBLK) a = LD_RLX(&part[2 * tid]) + LD_RLX(&part[2 * tid + 1]);
        sh0[tid] = a;
        if (tid < 128) sh0[NTHR + tid] = 0.0;
        __syncthreads();
        for (int off = 256; off > 0; off >>= 1) {
            if (tid < off) sh0[tid] += sh0[tid + off];
            __syncthreads();
        }
        if (tid == 0) out[0] = (float)(0.5 * sh0[0] / (double)TOTAL);
    }
}

extern "C" void kernel_launch(void* const* d_in, const int* in_sizes, int n_in,
                              void* d_out, int out_size, void* d_ws, size_t ws_size,
                              hipStream_t stream) {
    const float* pred = (const float*)d_in[0];
    const float* gt   = (const float*)d_in[1];
    char* ws = (char*)d_ws;
    uint64_t* packed = (uint64_t*)(ws + OFF_PACK);
    int*      ctrl   = (int*)(ws + OFF_CTRL);
    double*   part   = (double*)(ws + OFF_PART);
    uint64_t* haloT  = (uint64_t*)(ws + OFF_HT);
    uint64_t* haloB  = (uint64_t*)(ws + OFF_HB);

    fused_blur<<<NIMG * 64, 256, 0, stream>>>(gt, packed, ctrl);
    skel<<<NBLK, NTHR, 0, stream>>>(packed, (const float4*)pred, (const float4*)gt,
                                    ctrl, part, haloT, haloB, (float*)d_out);
}

// Round 6
// 188.191 us; speedup vs baseline: 1.2816x; 1.2816x over previous
//
#include <hip/hip_runtime.h>
#include <stdint.h>
#include <math.h>

static constexpr int NIMG  = 16;
static constexpr int HH    = 512;
static constexpr int WW    = 512;
static constexpr int TOTAL = NIMG * HH * WW;   // 4,194,304
static constexpr int WPR   = WW / 64;          // 8 qwords per row
static constexpr int QPI   = HH * WPR;         // 4096 qwords per image
static constexpr int NQ    = TOTAL / 64;       // 65,536
static constexpr int MAXIT = 128;
static constexpr int SW    = 9;                // padded LDS row stride in qwords (72B: 2-way banks, free)
static constexpr int RBLK  = 2048;             // reduce blocks

// workspace layout (bytes)
static constexpr size_t OFF_PACK = 0;                      // u64[NQ] packed bitmap
static constexpr size_t OFF_TICK = (size_t)NQ * 8;         // int ticket (+pad)
static constexpr size_t OFF_PART = OFF_TICK + 8;           // double[RBLK*2]

#define LD_RLX(p)   __hip_atomic_load((p), __ATOMIC_RELAXED, __HIP_MEMORY_SCOPE_AGENT)
#define ST_RLX(p,v) __hip_atomic_store((p), (v), __ATOMIC_RELAXED, __HIP_MEMORY_SCOPE_AGENT)

// gaussian taps exactly like numpy (f64 exp, sequential /sum, cast f32) — bit-compatible (r5: absmax 0)
__device__ __forceinline__ void make_gk(float* gks) {
    if (threadIdx.x < 9) {
        double ssum = 0.0;
        for (int i = 0; i < 9; ++i) { double x = (double)(i - 4); ssum += exp(-0.5 * x * x); }
        double x = (double)((int)threadIdx.x - 4);
        gks[threadIdx.x] = (float)(exp(-0.5 * x * x) / ssum);
    }
}

// --- fused separable blur + threshold + bit-pack. 64x64 output tile per block. (unchanged from r5)
__global__ void __launch_bounds__(256) fused_blur(const float* __restrict__ gt,
                                                  uint64_t* __restrict__ packed,
                                                  int* __restrict__ tick) {
    __shared__ float tin[72 * 72];
    __shared__ float tv[64 * 72];
    __shared__ float gks[9];
    const int tid = threadIdx.x;
    if (blockIdx.x == 0 && tid == 0) *tick = 0;      // re-zero ticket every call (ws is poisoned)
    make_gk(gks);
    const int img  = blockIdx.x >> 6;
    const int tile = blockIdx.x & 63;
    const int oy = (tile >> 3) << 6, ox = (tile & 7) << 6;
    const float* G = gt + (size_t)img * (HH * WW);
    for (int i = tid; i < 72 * 72; i += 256) {
        int r = i / 72, c = i - r * 72;
        int gy = oy - 4 + r, gx = ox - 4 + c;
        gy = gy < 0 ? -gy - 1 : (gy >= HH ? 2 * HH - 1 - gy : gy);   // symmetric pad
        gx = gx < 0 ? -gx - 1 : (gx >= WW ? 2 * WW - 1 - gx : gx);
        tin[i] = G[gy * WW + gx];
    }
    __syncthreads();
    for (int i = tid; i < 64 * 72; i += 256) {       // vertical pass first (axis=1, like ref)
        int r = i / 72, c = i - r * 72;
        float s = 0.f;
#pragma unroll
        for (int t = 0; t < 9; ++t) s += gks[t] * tin[(r + t) * 72 + c];
        tv[i] = s;
    }
    __syncthreads();
    const int lane = tid & 63, w = tid >> 6;
    for (int j = 0; j < 16; ++j) {                   // horizontal pass + threshold + pack
        int yr = w * 16 + j;
        float s = 0.f;
#pragma unroll
        for (int t = 0; t < 9; ++t) s += gks[t] * tv[yr * 72 + lane + t];
        uint64_t m = __ballot(s > 0.1f);
        if (lane == 0) packed[(size_t)img * QPI + (oy + yr) * WPR + (ox >> 6)] = m;
    }
}

// full adder on 64 bit-lanes
__device__ __forceinline__ void fa(uint64_t a, uint64_t b, uint64_t c, uint64_t& s, uint64_t& cy) {
    uint64_t axb = a ^ b;
    s  = axb ^ c;
    cy = (a & b) | (c & axb);
}

// bit-sliced Zhang-Suen delete mask (verified exact, rounds 2-5)
__device__ __forceinline__ uint64_t zs_del(uint64_t cc, uint64_t nc, uint64_t sc, uint64_t cw, uint64_t ce,
                                           uint64_t nw, uint64_t ne, uint64_t sw, uint64_t se, int step) {
    uint64_t p2 = nc;
    uint64_t p3 = (nc >> 1) | (ne << 63);
    uint64_t p4 = (cc >> 1) | (ce << 63);
    uint64_t p5 = (sc >> 1) | (se << 63);
    uint64_t p6 = sc;
    uint64_t p7 = (sc << 1) | (sw >> 63);
    uint64_t p8 = (cc << 1) | (cw >> 63);
    uint64_t p9 = (nc << 1) | (nw >> 63);

    uint64_t s1, k1, s2, k2;
    fa(p2, p3, p4, s1, k1);
    fa(p5, p6, p7, s2, k2);
    uint64_t s3 = p8 ^ p9, k3 = p8 & p9;
    uint64_t b0, k4;
    fa(s1, s2, s3, b0, k4);
    uint64_t t1, t2;
    fa(k1, k2, k3, t1, t2);
    uint64_t b1 = t1 ^ k4;
    uint64_t k5 = t1 & k4;
    uint64_t b2 = t2 ^ k5;
    uint64_t b3 = t2 & k5;
    uint64_t condB = (b1 | b2 | b3) & ~(b3 | (b0 & b1 & b2));

    uint64_t q0 = ~p2 & p3, q1 = ~p3 & p4, q2 = ~p4 & p5, q3 = ~p5 & p6;
    uint64_t q4 = ~p6 & p7, q5 = ~p7 & p8, q6 = ~p8 & p9, q7 = ~p9 & p2;
    uint64_t u1, v1, u2, v2;
    fa(q0, q1, q2, u1, v1);
    fa(q3, q4, q5, u2, v2);
    uint64_t u3 = q6 ^ q7, v3 = q6 & q7;
    uint64_t a0, v4;
    fa(u1, u2, u3, a0, v4);
    uint64_t w1, w2;
    fa(v1, v2, v3, w1, w2);
    uint64_t a1 = w1 ^ v4;
    uint64_t ka = w1 & v4;
    uint64_t a2 = w2 ^ ka;
    uint64_t a3 = w2 & ka;
    uint64_t condA = a0 & ~a1 & ~a2 & ~a3;

    uint64_t nc1, nc2;
    if (step == 0) { nc1 = ~(p2 & p4 & p6); nc2 = ~(p4 & p6 & p8); }
    else           { nc1 = ~(p2 & p4 & p8); nc2 = ~(p2 & p6 & p8); }

    return cc & condB & condA & nc1 & nc2;
}

// one sub-step: thread walks a 4-row column of qwords, rotating row registers (3 new loads/row)
__device__ __forceinline__ int zs_sub(const uint64_t* __restrict__ cur, uint64_t* __restrict__ nxt,
                                      int step, int wx, int y0, bool xw, bool xe) {
    int ch = 0;
    int b = y0 * SW + wx;
    uint64_t nwr, ncr, ner, cwr, ccr, cer;
    if (y0 > 0) {
        ncr = cur[b - SW];
        nwr = xw ? cur[b - SW - 1] : 0;
        ner = xe ? cur[b - SW + 1] : 0;
    } else { nwr = 0; ncr = 0; ner = 0; }
    ccr = cur[b];
    cwr = xw ? cur[b - 1] : 0;
    cer = xe ? cur[b + 1] : 0;
#pragma unroll
    for (int r = 0; r < 4; ++r) {
        uint64_t swr, scr, ser;
        if (y0 + r < HH - 1) {
            scr = cur[b + SW];
            swr = xw ? cur[b + SW - 1] : 0;
            ser = xe ? cur[b + SW + 1] : 0;
        } else { swr = 0; scr = 0; ser = 0; }
        uint64_t out = ccr;
        if (ccr) {
            uint64_t del = zs_del(ccr, ncr, scr, cwr, cer, nwr, ner, swr, ser, step);
            out = ccr & ~del;
            ch |= (del != 0ull);
        }
        nxt[b] = out;
        nwr = cwr; ncr = ccr; ner = cer;
        cwr = swr; ccr = scr; cer = ser;
        b += SW;
    }
    return ch;
}

// --- one workgroup per image, whole loop in LDS, intra-block sync only (r3 structure, optimized)
__global__ void __launch_bounds__(1024) skel_kernel(uint64_t* __restrict__ g) {
    __shared__ uint64_t SA[HH * SW];   // 36,864 B (padded stride)
    __shared__ uint64_t SB[HH * SW];
    __shared__ int chflag;
    const int tid = threadIdx.x;
    uint64_t* gimg = g + (size_t)blockIdx.x * QPI;

    for (int i = tid; i < QPI; i += 1024) SA[(i >> 3) * SW + (i & 7)] = gimg[i];
    if (tid == 0) chflag = 0;
    __syncthreads();

    const int wx = tid & 7;
    const int y0 = (tid >> 3) * 4;
    const bool xw = wx > 0, xe = wx < WPR - 1;

    for (int it = 0; it < MAXIT; ++it) {
        int ch = zs_sub(SA, SB, 0, wx, y0, xw, xe);
        __syncthreads();
        ch |= zs_sub(SB, SA, 1, wx, y0, xw, xe);
        if (__any(ch) && (tid & 63) == 0) atomicOr(&chflag, 1);
        __syncthreads();                 // SA writes + chflag visible
        int stop = (chflag == 0);
        __syncthreads();                 // everyone has read chflag
        if (tid == 0) chflag = 0;        // reset strictly before next iteration's atomicOr
        if (stop) break;                 // uniform
    }

    for (int i = tid; i < QPI; i += 1024) gimg[i] = SA[(i >> 3) * SW + (i & 7)];
}

// --- loss reduction: per-block partials + ticket'd last-block finalize (no global atomics on data)
__global__ void __launch_bounds__(256) reduce_kernel(const float4* __restrict__ pred4, const float4* __restrict__ gt4,
                                                     const uint64_t* __restrict__ mask,
                                                     double* __restrict__ part, int* __restrict__ tick,
                                                     float* __restrict__ out) {
    __shared__ double sh0[256];
    __shared__ double sh1[256];
    __shared__ int lastf;
    const int tid = threadIdx.x;
    double a0 = 0.0, a1 = 0.0;
    const int N4 = TOTAL / 4;
    for (int i = blockIdx.x * 256 + tid; i < N4; i += RBLK * 256) {
        float4 pv = pred4[i];
        float4 gv = gt4[i];
        uint64_t mq = mask[i >> 4];
        int shb = (i & 15) << 2;
        double d, d2;
        d = (double)(pv.x - gv.x); d2 = d * d; a0 += d2; if ((mq >> (shb    )) & 1) a1 += d2;
        d = (double)(pv.y - gv.y); d2 = d * d; a0 += d2; if ((mq >> (shb + 1)) & 1) a1 += d2;
        d = (double)(pv.z - gv.z); d2 = d * d; a0 += d2; if ((mq >> (shb + 2)) & 1) a1 += d2;
        d = (double)(pv.w - gv.w); d2 = d * d; a0 += d2; if ((mq >> (shb + 3)) & 1) a1 += d2;
    }
    sh0[tid] = a0;
    sh1[tid] = a1;
    __syncthreads();
    for (int off = 128; off > 0; off >>= 1) {
        if (tid < off) { sh0[tid] += sh0[tid + off]; sh1[tid] += sh1[tid + off]; }
        __syncthreads();
    }
    if (tid == 0) {
        ST_RLX(&part[2 * blockIdx.x],     sh0[0]);
        ST_RLX(&part[2 * blockIdx.x + 1], sh1[0]);
        int pos = __hip_atomic_fetch_add(tick, 1, __ATOMIC_ACQ_REL, __HIP_MEMORY_SCOPE_AGENT);
        lastf = (pos == RBLK - 1);       // ACQ on the add makes earlier blocks' partials visible
    }
    __syncthreads();
    if (lastf) {
        double a = 0.0;
        for (int i = tid; i < RBLK; i += 256) a += LD_RLX(&part[2 * i]) + LD_RLX(&part[2 * i + 1]);
        sh0[tid] = a;
        __syncthreads();
        for (int off = 128; off > 0; off >>= 1) {
            if (tid < off) sh0[tid] += sh0[tid + off];
            __syncthreads();
        }
        if (tid == 0) out[0] = (float)(0.5 * sh0[0] / (double)TOTAL);
    }
}

extern "C" void kernel_launch(void* const* d_in, const int* in_sizes, int n_in,
                              void* d_out, int out_size, void* d_ws, size_t ws_size,
                              hipStream_t stream) {
    const float* pred = (const float*)d_in[0];
    const float* gt   = (const float*)d_in[1];
    char* ws = (char*)d_ws;
    uint64_t* packed = (uint64_t*)(ws + OFF_PACK);
    int*      tick   = (int*)(ws + OFF_TICK);
    double*   part   = (double*)(ws + OFF_PART);

    fused_blur<<<NIMG * 64, 256, 0, stream>>>(gt, packed, tick);
    skel_kernel<<<NIMG, 1024, 0, stream>>>(packed);
    reduce_kernel<<<RBLK, 256, 0, stream>>>((const float4*)pred, (const float4*)gt,
                                            packed, part, tick, (float*)d_out);
}

// Round 8
// 138.245 us; speedup vs baseline: 1.7446x; 1.3613x over previous
//
#include <hip/hip_runtime.h>
#include <stdint.h>
#include <math.h>

static constexpr int NIMG  = 16;
static constexpr int HH    = 512;
static constexpr int WW    = 512;
static constexpr int TOTAL = NIMG * HH * WW;   // 4,194,304
static constexpr int WPR   = WW / 64;          // 8 qwords per row
static constexpr int QPI   = HH * WPR;         // 4096 qwords per image
static constexpr int NQ    = TOTAL / 64;       // 65,536
static constexpr int MAXIT = 128;
static constexpr int SW    = 9;                // padded LDS row stride (72B: 2-way banks, free)
static constexpr int RBLK  = 1024;             // reduce blocks

// workspace layout (bytes)
static constexpr size_t OFF_PACK = 0;                      // u64[NQ] packed bitmap
static constexpr size_t OFF_PART = (size_t)NQ * 8;         // double[RBLK*2]

// gaussian taps exactly like numpy (f64 exp, sequential /sum, cast f32) — bit-compatible (r5/r6: absmax 0)
__device__ __forceinline__ void make_gk(float* gks) {
    if (threadIdx.x < 9) {
        double ssum = 0.0;
        for (int i = 0; i < 9; ++i) { double x = (double)(i - 4); ssum += exp(-0.5 * x * x); }
        double x = (double)((int)threadIdx.x - 4);
        gks[threadIdx.x] = (float)(exp(-0.5 * x * x) / ssum);
    }
}

// --- fused separable blur + threshold + bit-pack. 64x64 output tile per block. (unchanged)
__global__ void __launch_bounds__(256) fused_blur(const float* __restrict__ gt,
                                                  uint64_t* __restrict__ packed) {
    __shared__ float tin[72 * 72];
    __shared__ float tv[64 * 72];
    __shared__ float gks[9];
    const int tid = threadIdx.x;
    make_gk(gks);
    const int img  = blockIdx.x >> 6;
    const int tile = blockIdx.x & 63;
    const int oy = (tile >> 3) << 6, ox = (tile & 7) << 6;
    const float* G = gt + (size_t)img * (HH * WW);
    for (int i = tid; i < 72 * 72; i += 256) {
        int r = i / 72, c = i - r * 72;
        int gy = oy - 4 + r, gx = ox - 4 + c;
        gy = gy < 0 ? -gy - 1 : (gy >= HH ? 2 * HH - 1 - gy : gy);   // symmetric pad
        gx = gx < 0 ? -gx - 1 : (gx >= WW ? 2 * WW - 1 - gx : gx);
        tin[i] = G[gy * WW + gx];
    }
    __syncthreads();
    for (int i = tid; i < 64 * 72; i += 256) {       // vertical pass first (axis=1, like ref)
        int r = i / 72, c = i - r * 72;
        float s = 0.f;
#pragma unroll
        for (int t = 0; t < 9; ++t) s += gks[t] * tin[(r + t) * 72 + c];
        tv[i] = s;
    }
    __syncthreads();
    const int lane = tid & 63, w = tid >> 6;
    for (int j = 0; j < 16; ++j) {                   // horizontal pass + threshold + pack
        int yr = w * 16 + j;
        float s = 0.f;
#pragma unroll
        for (int t = 0; t < 9; ++t) s += gks[t] * tv[yr * 72 + lane + t];
        uint64_t m = __ballot(s > 0.1f);
        if (lane == 0) packed[(size_t)img * QPI + (oy + yr) * WPR + (ox >> 6)] = m;
    }
}

// full adder on 64 bit-lanes
__device__ __forceinline__ void fa(uint64_t a, uint64_t b, uint64_t c, uint64_t& s, uint64_t& cy) {
    uint64_t axb = a ^ b;
    s  = axb ^ c;
    cy = (a & b) | (c & axb);
}

// bit-sliced Zhang-Suen delete mask (verified exact, rounds 2-6)
__device__ __forceinline__ uint64_t zs_del(uint64_t cc, uint64_t nc, uint64_t sc, uint64_t cw, uint64_t ce,
                                           uint64_t nw, uint64_t ne, uint64_t sw, uint64_t se, int step) {
    uint64_t p2 = nc;
    uint64_t p3 = (nc >> 1) | (ne << 63);
    uint64_t p4 = (cc >> 1) | (ce << 63);
    uint64_t p5 = (sc >> 1) | (se << 63);
    uint64_t p6 = sc;
    uint64_t p7 = (sc << 1) | (sw >> 63);
    uint64_t p8 = (cc << 1) | (cw >> 63);
    uint64_t p9 = (nc << 1) | (nw >> 63);

    uint64_t s1, k1, s2, k2;
    fa(p2, p3, p4, s1, k1);
    fa(p5, p6, p7, s2, k2);
    uint64_t s3 = p8 ^ p9, k3 = p8 & p9;
    uint64_t b0, k4;
    fa(s1, s2, s3, b0, k4);
    uint64_t t1, t2;
    fa(k1, k2, k3, t1, t2);
    uint64_t b1 = t1 ^ k4;
    uint64_t k5 = t1 & k4;
    uint64_t b2 = t2 ^ k5;
    uint64_t b3 = t2 & k5;
    uint64_t condB = (b1 | b2 | b3) & ~(b3 | (b0 & b1 & b2));

    uint64_t q0 = ~p2 & p3, q1 = ~p3 & p4, q2 = ~p4 & p5, q3 = ~p5 & p6;
    uint64_t q4 = ~p6 & p7, q5 = ~p7 & p8, q6 = ~p8 & p9, q7 = ~p9 & p2;
    uint64_t u1, v1, u2, v2;
    fa(q0, q1, q2, u1, v1);
    fa(q3, q4, q5, u2, v2);
    uint64_t u3 = q6 ^ q7, v3 = q6 & q7;
    uint64_t a0, v4;
    fa(u1, u2, u3, a0, v4);
    uint64_t w1, w2;
    fa(v1, v2, v3, w1, w2);
    uint64_t a1 = w1 ^ v4;
    uint64_t ka = w1 & v4;
    uint64_t a2 = w2 ^ ka;
    uint64_t a3 = w2 & ka;
    uint64_t condA = a0 & ~a1 & ~a2 & ~a3;

    uint64_t nc1, nc2;
    if (step == 0) { nc1 = ~(p2 & p4 & p6); nc2 = ~(p4 & p6 & p8); }
    else           { nc1 = ~(p2 & p4 & p8); nc2 = ~(p2 & p6 & p8); }

    return cc & condB & condA & nc1 & nc2;
}

// one sub-step: thread walks a 4-row column of qwords, rotating row registers (3 new loads/row)
__device__ __forceinline__ int zs_sub(const uint64_t* __restrict__ cur, uint64_t* __restrict__ nxt,
                                      int step, int wx, int y0, bool xw, bool xe) {
    int ch = 0;
    int b = y0 * SW + wx;
    uint64_t nwr, ncr, ner, cwr, ccr, cer;
    if (y0 > 0) {
        ncr = cur[b - SW];
        nwr = xw ? cur[b - SW - 1] : 0;
        ner = xe ? cur[b - SW + 1] : 0;
    } else { nwr = 0; ncr = 0; ner = 0; }
    ccr = cur[b];
    cwr = xw ? cur[b - 1] : 0;
    cer = xe ? cur[b + 1] : 0;
#pragma unroll
    for (int r = 0; r < 4; ++r) {
        uint64_t swr, scr, ser;
        if (y0 + r < HH - 1) {
            scr = cur[b + SW];
            swr = xw ? cur[b + SW - 1] : 0;
            ser = xe ? cur[b + SW + 1] : 0;
        } else { swr = 0; scr = 0; ser = 0; }
        uint64_t out = ccr;
        if (ccr) {
            uint64_t del = zs_del(ccr, ncr, scr, cwr, cer, nwr, ner, swr, ser, step);
            out = ccr & ~del;
            ch |= (del != 0ull);
        }
        nxt[b] = out;
        nwr = cwr; ncr = ccr; ner = cer;
        cwr = swr; ccr = scr; cer = ser;
        b += SW;
    }
    return ch;
}

// --- one workgroup per image, whole loop in LDS; 2 barriers/iteration via parity flags
__global__ void __launch_bounds__(1024) skel_kernel(uint64_t* __restrict__ g) {
    __shared__ uint64_t SA[HH * SW];   // 36,864 B (padded stride)
    __shared__ uint64_t SB[HH * SW];
    __shared__ int f2[2];
    const int tid = threadIdx.x;
    uint64_t* gimg = g + (size_t)blockIdx.x * QPI;

    for (int i = tid; i < QPI; i += 1024) SA[(i >> 3) * SW + (i & 7)] = gimg[i];
    if (tid == 0) { f2[0] = 0; f2[1] = 0; }
    __syncthreads();

    const int wx = tid & 7;
    const int y0 = (tid >> 3) * 4;
    const bool xw = wx > 0, xe = wx < WPR - 1;

    for (int it = 0; it < MAXIT; ++it) {
        const int p = it & 1;
        int ch = zs_sub(SA, SB, 0, wx, y0, xw, xe);
        __syncthreads();                         // SB complete; f2[p^1] reset visible
        ch |= zs_sub(SB, SA, 1, wx, y0, xw, xe);
        if (__any(ch) && (tid & 63) == 0) atomicOr(&f2[p], 1);
        __syncthreads();                         // SA complete; all atomicOrs into f2[p] done
        int stop = (f2[p] == 0);                 // uniform read
        if (tid == 0) f2[p ^ 1] = 0;             // reset other parity; ordered by next iter's barrier
        if (stop) break;
    }

    for (int i = tid; i < QPI; i += 1024) gimg[i] = SA[(i >> 3) * SW + (i & 7)];
}

// --- loss reduction: per-block f64 partials, unconditional writes, NO cross-block coordination
__global__ void __launch_bounds__(256) reduce_kernel(const float4* __restrict__ pred4, const float4* __restrict__ gt4,
                                                     const uint64_t* __restrict__ mask,
                                                     double* __restrict__ part) {
    __shared__ double sh0[256];
    __shared__ double sh1[256];
    const int tid = threadIdx.x;
    double a0 = 0.0, a1 = 0.0;
    const int N4 = TOTAL / 4;
    for (int i = blockIdx.x * 256 + tid; i < N4; i += RBLK * 256) {
        float4 pv = pred4[i];
        float4 gv = gt4[i];
        uint64_t mq = mask[i >> 4];
        int shb = (i & 15) << 2;
        double d, d2;
        d = (double)(pv.x - gv.x); d2 = d * d; a0 += d2; if ((mq >> (shb    )) & 1) a1 += d2;
        d = (double)(pv.y - gv.y); d2 = d * d; a0 += d2; if ((mq >> (shb + 1)) & 1) a1 += d2;
        d = (double)(pv.z - gv.z); d2 = d * d; a0 += d2; if ((mq >> (shb + 2)) & 1) a1 += d2;
        d = (double)(pv.w - gv.w); d2 = d * d; a0 += d2; if ((mq >> (shb + 3)) & 1) a1 += d2;
    }
    sh0[tid] = a0;
    sh1[tid] = a1;
    __syncthreads();
    for (int off = 128; off > 0; off >>= 1) {
        if (tid < off) { sh0[tid] += sh0[tid + off]; sh1[tid] += sh1[tid + off]; }
        __syncthreads();
    }
    if (tid == 0) {
        part[2 * blockIdx.x]     = sh0[0];
        part[2 * blockIdx.x + 1] = sh1[0];
    }
}

// --- single-block finalize: sum RBLK*2 doubles, write the loss
__global__ void __launch_bounds__(256) finalize_kernel(const double* __restrict__ part,
                                                       float* __restrict__ out) {
    __shared__ double sh[256];
    const int tid = threadIdx.x;
    double a = 0.0;
    for (int i = tid; i < RBLK; i += 256) a += part[2 * i] + part[2 * i + 1];
    sh[tid] = a;
    __syncthreads();
    for (int off = 128; off > 0; off >>= 1) {
        if (tid < off) sh[tid] += sh[tid + off];
        __syncthreads();
    }
    if (tid == 0) out[0] = (float)(0.5 * sh[0] / (double)TOTAL);
}

extern "C" void kernel_launch(void* const* d_in, const int* in_sizes, int n_in,
                              void* d_out, int out_size, void* d_ws, size_t ws_size,
                              hipStream_t stream) {
    const float* pred = (const float*)d_in[0];
    const float* gt   = (const float*)d_in[1];
    char* ws = (char*)d_ws;
    uint64_t* packed = (uint64_t*)(ws + OFF_PACK);
    double*   part   = (double*)(ws + OFF_PART);

    fused_blur<<<NIMG * 64, 256, 0, stream>>>(gt, packed);
    skel_kernel<<<NIMG, 1024, 0, stream>>>(packed);
    reduce_kernel<<<RBLK, 256, 0, stream>>>((const float4*)pred, (const float4*)gt, packed, part);
    finalize_kernel<<<1, 256, 0, stream>>>(part, (float*)d_out);
}